// Round 1
// baseline (417.254 us; speedup 1.0000x reference)
//
#include <hip/hip_runtime.h>
#include <hip/hip_bf16.h>

// Problem constants
#define D_MODEL 1024
#define NHEADS  16
#define HD      64
#define BATCH   2
#define SEQ     2048
#define NTOK    (BATCH * SEQ)   // 4096

typedef __attribute__((ext_vector_type(8))) short bf16x8;   // 8 bf16 (4 VGPRs)
typedef __attribute__((ext_vector_type(4))) float f32x4;    // MFMA C/D frag

static __device__ __forceinline__ short f2bf(float f) {
    union { float f; unsigned u; } x; x.f = f;
    unsigned r = (x.u + 0x7fffu + ((x.u >> 16) & 1u)) >> 16;  // RNE
    return (short)r;
}

// ---------------------------------------------------------------------------
// Cast x (fp32 -> bf16), vectorized x4
// ---------------------------------------------------------------------------
__global__ void cast_x_kernel(const float* __restrict__ in, short* __restrict__ out, int n4) {
    int i = blockIdx.x * blockDim.x + threadIdx.x;
    if (i < n4) {
        float4 v = ((const float4*)in)[i];
        short4 o;
        o.x = f2bf(v.x); o.y = f2bf(v.y); o.z = f2bf(v.z); o.w = f2bf(v.w);
        ((short4*)out)[i] = o;
    }
}

// ---------------------------------------------------------------------------
// Transpose + cast: in [R][C] fp32  ->  out [C][R] bf16   (32x32 LDS tiles)
// ---------------------------------------------------------------------------
__global__ void transpose_cast_kernel(const float* __restrict__ in, short* __restrict__ out,
                                      int R, int C) {
    __shared__ float tile[32][33];
    int bc = blockIdx.x * 32;   // col base (input)
    int br = blockIdx.y * 32;   // row base (input)
    int tx = threadIdx.x, ty = threadIdx.y;
    #pragma unroll
    for (int i = 0; i < 32; i += 8)
        tile[ty + i][tx] = in[(br + ty + i) * C + bc + tx];
    __syncthreads();
    #pragma unroll
    for (int i = 0; i < 32; i += 8)
        out[(bc + ty + i) * R + br + tx] = f2bf(tile[tx][ty + i]);
}

// ---------------------------------------------------------------------------
// NT GEMM: C[M][N] = A[M][K] * B^T  where B is stored transposed as BT[N][K].
// Both operand fragments are K-contiguous -> direct 16B global loads.
// 128x128 block tile, 4 waves (2x2), each wave 64x64 = 4x4 MFMA 16x16x32 frags.
// M,N,K all divisible by 128/32 here, no bounds checks.
// ---------------------------------------------------------------------------
template <bool OUT_F32>
__global__ __launch_bounds__(256) void gemm_nt(const short* __restrict__ A,
                                               const short* __restrict__ BT,
                                               void* __restrict__ C,
                                               int M, int N, int K) {
    int tid  = threadIdx.x;
    int lane = tid & 63;
    int w    = tid >> 6;       // 0..3
    int quad = lane >> 4;      // 0..3
    int l16  = lane & 15;

    int m0 = blockIdx.y * 128 + (w >> 1) * 64;
    int n0 = blockIdx.x * 128 + (w & 1) * 64;

    f32x4 acc[4][4] = {};

    const short* Abase = A  + (long)(m0 + l16) * K + quad * 8;
    const short* Bbase = BT + (long)(n0 + l16) * K + quad * 8;

    for (int k0 = 0; k0 < K; k0 += 32) {
        bf16x8 a[4], b[4];
        #pragma unroll
        for (int i = 0; i < 4; i++) {
            a[i] = *(const bf16x8*)(Abase + (long)(i * 16) * K + k0);
            b[i] = *(const bf16x8*)(Bbase + (long)(i * 16) * K + k0);
        }
        #pragma unroll
        for (int i = 0; i < 4; i++)
            #pragma unroll
            for (int j = 0; j < 4; j++)
                acc[i][j] = __builtin_amdgcn_mfma_f32_16x16x32_bf16(a[i], b[j], acc[i][j], 0, 0, 0);
    }

    // C/D layout: col = lane&15, row = quad*4 + reg   (m89/m91 verified)
    #pragma unroll
    for (int i = 0; i < 4; i++)
        #pragma unroll
        for (int j = 0; j < 4; j++)
            #pragma unroll
            for (int r = 0; r < 4; r++) {
                int row = m0 + i * 16 + quad * 4 + r;
                int col = n0 + j * 16 + l16;
                float v = acc[i][j][r];
                if (OUT_F32) ((float*)C)[(long)row * N + col] = v;
                else         ((short*)C)[(long)row * N + col] = f2bf(v);
            }
}

// ---------------------------------------------------------------------------
// Flash attention. qkv: [NTOK][3072] bf16 (q|k|v each 1024 wide, head h at
// col h*64). Grid: (SEQ/64, BATCH*NHEADS). Block 256 = 4 waves; wave owns 16
// query rows. Online softmax; P through LDS (C-layout -> A-layout); V staged
// in LDS. Output y: [NTOK][1024] bf16 with d = h*64 + hd.
// ---------------------------------------------------------------------------
__global__ __launch_bounds__(256) void flash_attn(const short* __restrict__ qkv,
                                                  short* __restrict__ y) {
    int tid  = threadIdx.x;
    int lane = tid & 63;
    int w    = tid >> 6;
    int quad = lane >> 4;
    int l16  = lane & 15;

    int bh = blockIdx.y;
    int b  = bh >> 4;
    int h  = bh & 15;
    int q0 = blockIdx.x * 64;
    int qw = q0 + w * 16;              // this wave's first query row

    __shared__ short Vs[32][64];       // V tile (32 keys x 64 hd), 4 KB
    __shared__ short Ps[4][16][32];    // per-wave P tile, 4 KB

    const long rs = 3072;
    const short* base = qkv + (long)b * SEQ * rs + h * HD;  // +0:q, +1024:k, +2048:v

    // Q fragments (A-operand: m = lane&15, k = quad*8+j), two 32-wide d-chunks
    bf16x8 aQ[2];
    #pragma unroll
    for (int c = 0; c < 2; c++)
        aQ[c] = *(const bf16x8*)(base + (long)(qw + l16) * rs + c * 32 + quad * 8);

    f32x4 O[4] = {};
    float m_r[4], l_r[4];
    #pragma unroll
    for (int r = 0; r < 4; r++) { m_r[r] = -1e30f; l_r[r] = 0.0f; }

    const float scale = 0.125f;  // 1/sqrt(64)

    for (int k0 = 0; k0 < SEQ; k0 += 32) {
        __syncthreads();  // protect Vs/Ps from previous iteration's readers
        // stage V tile: 256 threads x 8 contiguous bf16 (16B each)
        {
            int vr = tid >> 3;
            int vc = (tid & 7) * 8;
            *(bf16x8*)(&Vs[vr][vc]) =
                *(const bf16x8*)(base + (long)(k0 + vr) * rs + 2048 + vc);
        }

        // S = Q K^T : B-operand lane holds key = kc*16 + l16, k(d) = quad*8+j
        f32x4 Sf[2];
        #pragma unroll
        for (int kc = 0; kc < 2; kc++) {
            const short* kb = base + (long)(k0 + kc * 16 + l16) * rs + 1024;
            bf16x8 b0 = *(const bf16x8*)(kb + quad * 8);
            bf16x8 b1 = *(const bf16x8*)(kb + 32 + quad * 8);
            f32x4 z = {};
            z = __builtin_amdgcn_mfma_f32_16x16x32_bf16(aQ[0], b0, z, 0, 0, 0);
            z = __builtin_amdgcn_mfma_f32_16x16x32_bf16(aQ[1], b1, z, 0, 0, 0);
            Sf[kc] = z;
        }

        // online softmax (C-layout: row = quad*4+r, col = l16; row spans the
        // 16 lanes of a quad -> shfl_xor butterfly over offsets 1,2,4,8)
        float p0[4], p1[4], mt[4];
        #pragma unroll
        for (int r = 0; r < 4; r++) {
            p0[r] = Sf[0][r] * scale;
            p1[r] = Sf[1][r] * scale;
            mt[r] = fmaxf(p0[r], p1[r]);
        }
        #pragma unroll
        for (int off = 1; off < 16; off <<= 1)
            #pragma unroll
            for (int r = 0; r < 4; r++)
                mt[r] = fmaxf(mt[r], __shfl_xor(mt[r], off));

        float alpha[4], rsum[4];
        #pragma unroll
        for (int r = 0; r < 4; r++) {
            float mn = fmaxf(m_r[r], mt[r]);
            alpha[r] = __expf(m_r[r] - mn);
            m_r[r]   = mn;
            p0[r] = __expf(p0[r] - mn);
            p1[r] = __expf(p1[r] - mn);
            rsum[r] = p0[r] + p1[r];
        }
        #pragma unroll
        for (int off = 1; off < 16; off <<= 1)
            #pragma unroll
            for (int r = 0; r < 4; r++)
                rsum[r] += __shfl_xor(rsum[r], off);
        #pragma unroll
        for (int r = 0; r < 4; r++)
            l_r[r] = l_r[r] * alpha[r] + rsum[r];

        // rescale O
        #pragma unroll
        for (int j = 0; j < 4; j++)
            #pragma unroll
            for (int r = 0; r < 4; r++)
                O[j][r] *= alpha[r];

        // write P (bf16) to LDS in row-major [16 q][32 key]
        #pragma unroll
        for (int r = 0; r < 4; r++) {
            Ps[w][quad * 4 + r][l16]      = f2bf(p0[r]);
            Ps[w][quad * 4 + r][16 + l16] = f2bf(p1[r]);
        }
        __syncthreads();

        // PV: A = P (A-layout read: m=l16, k=quad*8+j), B = V from LDS
        bf16x8 aP = *(const bf16x8*)(&Ps[w][l16][quad * 8]);
        #pragma unroll
        for (int j = 0; j < 4; j++) {
            bf16x8 bV;
            #pragma unroll
            for (int jj = 0; jj < 8; jj++)
                bV[jj] = Vs[quad * 8 + jj][j * 16 + l16];
            O[j] = __builtin_amdgcn_mfma_f32_16x16x32_bf16(aP, bV, O[j], 0, 0, 0);
        }
    }

    // epilogue: O / l, write y[b,t, h*64 + d]
    #pragma unroll
    for (int j = 0; j < 4; j++)
        #pragma unroll
        for (int r = 0; r < 4; r++) {
            float v = O[j][r] / l_r[r];
            int row = qw + quad * 4 + r;
            y[((long)b * SEQ + row) * D_MODEL + h * HD + j * 16 + l16] = f2bf(v);
        }
}

// ---------------------------------------------------------------------------
// Workspace layout (bytes):
//   x_bf   @ 0         : 4096*1024*2  =  8388608
//   WqkvT  @ 8388608   : 3072*1024*2  =  6291456
//   WoT    @ 14680064  : 1024*1024*2  =  2097152
//   qkv    @ 16777216  : 4096*3072*2  = 25165824
//   y      @ 41943040  : 4096*1024*2  =  8388608
//   total 50331648 (48 MB)
// ---------------------------------------------------------------------------
extern "C" void kernel_launch(void* const* d_in, const int* in_sizes, int n_in,
                              void* d_out, int out_size, void* d_ws, size_t ws_size,
                              hipStream_t stream) {
    const float* x    = (const float*)d_in[0];
    const float* Wqkv = (const float*)d_in[1];
    const float* Wo   = (const float*)d_in[2];

    char* ws = (char*)d_ws;
    short* x_bf  = (short*)(ws);
    short* WqkvT = (short*)(ws + 8388608);
    short* WoT   = (short*)(ws + 14680064);
    short* qkv   = (short*)(ws + 16777216);
    short* yb    = (short*)(ws + 41943040);

    cast_x_kernel<<<4096, 256, 0, stream>>>(x, x_bf, NTOK * D_MODEL / 4);
    transpose_cast_kernel<<<dim3(3 * D_MODEL / 32, D_MODEL / 32), dim3(32, 8), 0, stream>>>(
        Wqkv, WqkvT, D_MODEL, 3 * D_MODEL);
    transpose_cast_kernel<<<dim3(D_MODEL / 32, D_MODEL / 32), dim3(32, 8), 0, stream>>>(
        Wo, WoT, D_MODEL, D_MODEL);

    // qkv = x @ Wqkv   [4096,1024] x [1024,3072] -> bf16
    gemm_nt<false><<<dim3(3 * D_MODEL / 128, NTOK / 128), 256, 0, stream>>>(
        x_bf, WqkvT, qkv, NTOK, 3 * D_MODEL, D_MODEL);

    // attention -> y [4096,1024] bf16
    flash_attn<<<dim3(SEQ / 64, BATCH * NHEADS), 256, 0, stream>>>(qkv, yb);

    // out = y @ Wo  -> fp32 d_out
    gemm_nt<true><<<dim3(D_MODEL / 128, NTOK / 128), 256, 0, stream>>>(
        yb, WoT, (float*)d_out, NTOK, D_MODEL, D_MODEL);
}